// Round 8
// baseline (1051.675 us; speedup 1.0000x reference)
//
#include <hip/hip_runtime.h>
#include <math.h>
#include <stdint.h>

// Problem constants (fixed instance)
#define LSEQ 2048
#define DM   1024
#define DI   2048
#define NC   32     // scan chunks per sequence
#define CL   64     // scan chunk length (NC*CL == LSEQ)

// ---------------------------------------------------------------------------
// Workspace layout (float units). Total 62,914,560 floats = 251.7 MB.
//  X  [0,          16777216)  : x half of in_proj output; later delta (in place)
//  Z  [16777216,   33554432)  : z half
//  U  [33554432,   50331648)  : conv output u -> y (in place, stays fp32)
//  S  [50331648,   58720256)  : A1' (hs split bf16[8192][2048]) until gemm1 done,
//                               then cs/sdt/xdbl/feats/Aws overlay
//  B1 [58720256,   62914560)  : B1' (in_proj split) -> B2' (out_proj split)
// ---------------------------------------------------------------------------
#define OFF_X     ((size_t)0)
#define OFF_Z     ((size_t)16777216)
#define OFF_U     ((size_t)33554432)
#define OFF_S     ((size_t)50331648)
#define OFF_CS    (OFF_S)                      // 4,194,304 floats
#define OFF_SDT   (OFF_S + 4194304)            //   262,144
#define OFF_XDBL  (OFF_S + 4456448)            //   786,432
#define OFF_FEAT  (OFF_S + 5242880)            //    65,536
#define OFF_AWS   (OFF_S + 5308448)            //    32,768
#define OFF_B1    ((size_t)58720256)

__device__ __forceinline__ float silu_(float x) { return x / (1.f + __expf(-x)); }
__device__ __forceinline__ float softplus_(float x) {
  return fmaxf(x, 0.f) + log1pf(__expf(-fabsf(x)));
}
__device__ __forceinline__ unsigned short f2bf(float x) {
  unsigned int u = __float_as_uint(x);
  u += 0x7fffu + ((u >> 16) & 1u);      // RNE (inputs finite)
  return (unsigned short)(u >> 16);
}
__device__ __forceinline__ float bf2f(unsigned short h) {
  return __uint_as_float(((unsigned int)h) << 16);
}

typedef __attribute__((ext_vector_type(8))) short bf16x8;
typedef __attribute__((ext_vector_type(4))) float f32x4;

__device__ __forceinline__ void gl2lds16(const void* g, void* l) {
  __builtin_amdgcn_global_load_lds(
      (const __attribute__((address_space(1))) unsigned int*)(uintptr_t)g,
      (__attribute__((address_space(3))) unsigned int*)(uintptr_t)l,
      16, 0, 0);
}

// ---------------------------------------------------------------------------
// Split fp32 -> [hi | lo] bf16 per row, two tensors in one dispatch.
// Each thread handles ONE float4. Tensor a = first na4 float4-slots.
// ---------------------------------------------------------------------------
__global__ __launch_bounds__(256) void split2_w(
    const float* __restrict__ a, unsigned short* __restrict__ oa, int ksa,
    size_t na4,
    const float* __restrict__ b, unsigned short* __restrict__ ob, int ksb)
{
  size_t i4 = ((size_t)blockIdx.x << 8) + threadIdx.x;
  const float* src; unsigned short* dst; int ks;
  if (i4 < na4) { src = a; dst = oa; ks = ksa; }
  else          { src = b; dst = ob; ks = ksb; i4 -= na4; }
  const size_t flat = i4 << 2;
  const int K = 1 << ks;
  const size_t row = flat >> ks;
  const int k = (int)(flat & (size_t)(K - 1));
  float4 v = *(const float4*)(src + flat);
  float f[4] = {v.x, v.y, v.z, v.w};
  unsigned short h[4], lo[4];
#pragma unroll
  for (int c = 0; c < 4; ++c) { h[c] = f2bf(f[c]); lo[c] = f2bf(f[c] - bf2f(h[c])); }
  unsigned short* o = dst + (row << (ks + 1)) + k;
  *(uint2*)(o)     = make_uint2((unsigned)h[0]  | ((unsigned)h[1]  << 16),
                                (unsigned)h[2]  | ((unsigned)h[3]  << 16));
  *(uint2*)(o + K) = make_uint2((unsigned)lo[0] | ((unsigned)lo[1] << 16),
                                (unsigned)lo[2] | ((unsigned)lo[3] << 16));
}

// ---------------------------------------------------------------------------
// Split-bf16 MFMA GEMM: C[M,N] = A·B^T, fp32-class accuracy via
// a_hi·b_hi + a_hi·b_lo + a_lo·b_hi for "full" column blocks (bn < nhi);
// hi·hi only for bn >= nhi (error budget: those cols feed silu gating only).
// A_FP32: A is fp32 [M][K]; hi/lo split happens in-register during staging
// (saves the separate split pass over y). Else A is bf16 [M][2K] [hi|lo].
// 128x128 tile, 4 waves, BK=32, 16x16x32 MFMA, XOR bank swizzle on LDS.
// Block swizzle: lin%8 = XCD; n-index = ((t&nmask)<<3)|xcd interleaves
// heavy/light tiles across XCDs; each XCD walks all m for its n-set.
// WRITE_SPLIT: cols<2048 -> C0, else C1.
// ---------------------------------------------------------------------------
template <int WRITE_SPLIT, int A_FP32>
__global__ __launch_bounds__(256) void gemm_mfma(
    const void* __restrict__ Avp, const unsigned short* __restrict__ Bp,
    float* __restrict__ C0, float* __restrict__ C1, int K, int ldc,
    int nxs, int nhi)
{
  __shared__ unsigned short AsH[128 * 32];
  __shared__ unsigned short AsL[128 * 32];
  __shared__ unsigned short BsH[128 * 32];
  __shared__ unsigned short BsL[128 * 32];
  const int tid = threadIdx.x;
  const int lin = blockIdx.y * gridDim.x + blockIdx.x;
  const int xcd = lin & 7;
  const int t = lin >> 3;
  const int nmask = (1 << nxs) - 1;
  const int bn = (((t & nmask) << 3) | xcd) << 7;
  const int bm = (t >> nxs) << 7;
  const int K2 = K * 2;
  const bool full = bn < nhi;

  const int wave = tid >> 6, lane = tid & 63;
  const int wm = (wave >> 1) << 6, wn = (wave & 1) << 6;
  const int lm = lane & 15, quad = lane >> 4;
  const int sw = (lm >> 1) & 3;        // reader swizzle (row>>1)&3 == (lm>>1)&3

  f32x4 acc[4][4] = {};

  // staging: thread tid fills LDS slots tid (rows 0..63) and tid+256
  // (rows 64..127); slot s=(r,q) takes global k-chunk q^((r>>1)&3).
  const int r0 = tid >> 2;
  const int kq = ((tid & 3) ^ ((r0 >> 1) & 3)) << 3;   // element offset
  const unsigned short* BgH0 = Bp + (size_t)(bn + r0) * K2 + kq;
  const unsigned short* BgH1 = Bp + (size_t)(bn + 64 + r0) * K2 + kq;
  unsigned short* lA0 = &AsH[(size_t)tid * 8];
  unsigned short* lA1 = &AsH[(size_t)(256 + tid) * 8];
  unsigned short* lAl0 = &AsL[(size_t)tid * 8];
  unsigned short* lAl1 = &AsL[(size_t)(256 + tid) * 8];
  unsigned short* lB0 = &BsH[(size_t)tid * 8];
  unsigned short* lB1 = &BsH[(size_t)(256 + tid) * 8];
  unsigned short* lBl0 = &BsL[(size_t)tid * 8];
  unsigned short* lBl1 = &BsL[(size_t)(256 + tid) * 8];

  const unsigned short* AgH0 = nullptr; const unsigned short* AgH1 = nullptr;
  const float* Af0 = nullptr; const float* Af1 = nullptr;
  if (A_FP32) {
    const float* Af = (const float*)Avp;
    Af0 = Af + (size_t)(bm + r0) * K + kq;
    Af1 = Af + (size_t)(bm + 64 + r0) * K + kq;
  } else {
    const unsigned short* Ab = (const unsigned short*)Avp;
    AgH0 = Ab + (size_t)(bm + r0) * K2 + kq;
    AgH1 = Ab + (size_t)(bm + 64 + r0) * K2 + kq;
  }

  for (int k0 = 0; k0 < K; k0 += 32) {
    __syncthreads();
    if (A_FP32) {
      float4 u0 = *(const float4*)(Af0 + k0);
      float4 u1 = *(const float4*)(Af0 + k0 + 4);
      float4 v0 = *(const float4*)(Af1 + k0);
      float4 v1 = *(const float4*)(Af1 + k0 + 4);
      float fu[8] = {u0.x,u0.y,u0.z,u0.w,u1.x,u1.y,u1.z,u1.w};
      float fv[8] = {v0.x,v0.y,v0.z,v0.w,v1.x,v1.y,v1.z,v1.w};
      unsigned int hu[4], lu[4], hv[4], lv[4];
#pragma unroll
      for (int c = 0; c < 4; ++c) {
        unsigned short h0 = f2bf(fu[2*c]),   l0 = f2bf(fu[2*c]   - bf2f(h0));
        unsigned short h1 = f2bf(fu[2*c+1]), l1 = f2bf(fu[2*c+1] - bf2f(h1));
        hu[c] = (unsigned)h0 | ((unsigned)h1 << 16);
        lu[c] = (unsigned)l0 | ((unsigned)l1 << 16);
        unsigned short g0 = f2bf(fv[2*c]),   m0 = f2bf(fv[2*c]   - bf2f(g0));
        unsigned short g1 = f2bf(fv[2*c+1]), m1 = f2bf(fv[2*c+1] - bf2f(g1));
        hv[c] = (unsigned)g0 | ((unsigned)g1 << 16);
        lv[c] = (unsigned)m0 | ((unsigned)m1 << 16);
      }
      *(uint4*)lA0  = make_uint4(hu[0], hu[1], hu[2], hu[3]);
      *(uint4*)lAl0 = make_uint4(lu[0], lu[1], lu[2], lu[3]);
      *(uint4*)lA1  = make_uint4(hv[0], hv[1], hv[2], hv[3]);
      *(uint4*)lAl1 = make_uint4(lv[0], lv[1], lv[2], lv[3]);
    } else {
      gl2lds16(AgH0 + k0, lA0);
      gl2lds16(AgH1 + k0, lA1);
      if (full) {
        gl2lds16(AgH0 + K + k0, lAl0);
        gl2lds16(AgH1 + K + k0, lAl1);
      }
    }
    gl2lds16(BgH0 + k0, lB0);
    gl2lds16(BgH1 + k0, lB1);
    if (full) {
      gl2lds16(BgH0 + K + k0, lBl0);
      gl2lds16(BgH1 + K + k0, lBl1);
    }
    __syncthreads();

    bf16x8 aH[4], bH[4];
#pragma unroll
    for (int i = 0; i < 4; ++i)
      aH[i] = *(const bf16x8*)&AsH[(wm + i * 16 + lm) * 32 + ((quad ^ sw) << 3)];
#pragma unroll
    for (int j = 0; j < 4; ++j)
      bH[j] = *(const bf16x8*)&BsH[(wn + j * 16 + lm) * 32 + ((quad ^ sw) << 3)];
#pragma unroll
    for (int i = 0; i < 4; ++i)
#pragma unroll
      for (int j = 0; j < 4; ++j)
        acc[i][j] = __builtin_amdgcn_mfma_f32_16x16x32_bf16(aH[i], bH[j], acc[i][j], 0, 0, 0);
    if (full) {
      bf16x8 aL[4], bL[4];
#pragma unroll
      for (int i = 0; i < 4; ++i)
        aL[i] = *(const bf16x8*)&AsL[(wm + i * 16 + lm) * 32 + ((quad ^ sw) << 3)];
#pragma unroll
      for (int j = 0; j < 4; ++j)
        bL[j] = *(const bf16x8*)&BsL[(wn + j * 16 + lm) * 32 + ((quad ^ sw) << 3)];
#pragma unroll
      for (int i = 0; i < 4; ++i)
#pragma unroll
        for (int j = 0; j < 4; ++j) {
          acc[i][j] = __builtin_amdgcn_mfma_f32_16x16x32_bf16(aH[i], bL[j], acc[i][j], 0, 0, 0);
          acc[i][j] = __builtin_amdgcn_mfma_f32_16x16x32_bf16(aL[i], bH[j], acc[i][j], 0, 0, 0);
        }
    }
  }

  // epilogue: C/D layout col=lane&15 (n, from B), row=quad*4+reg (m, from A)
  float* Cb = C0;
  int nb = bn;
  if (WRITE_SPLIT && bn >= 2048) { Cb = C1; nb = bn - 2048; }
#pragma unroll
  for (int i = 0; i < 4; ++i) {
    const int m = bm + wm + i * 16 + quad * 4;
#pragma unroll
    for (int j = 0; j < 4; ++j) {
      const int n = nb + wn + j * 16 + lm;
#pragma unroll
      for (int r = 0; r < 4; ++r)
        Cb[(size_t)(m + r) * ldc + n] = acc[i][j][r];
    }
  }
}

// ---------------------------------------------------------------------------
// fp32 NT GEMM (small shapes): C[M,N] = A[M,K]·B[N,K]^T. 64x64 tile, BK=16.
// EPI: 0 none, 1 softplus(acc + bias[n]).
// ---------------------------------------------------------------------------
template <int EPI>
__global__ __launch_bounds__(256) void gemm_nt(
    const float* __restrict__ A, int lda,
    const float* __restrict__ B, int ldb,
    float* __restrict__ C, int ldc,
    int N, int K, const float* __restrict__ bias)
{
  __shared__ float As[16][68];
  __shared__ float Bs[16][68];
  const int tid = threadIdx.x;
  const int bm = blockIdx.y << 6;
  const int bn = blockIdx.x << 6;
  const int lr = tid >> 2;
  const int lk = (tid & 3) << 2;
  const int tx = tid & 15, ty = tid >> 4;

  float acc[4][4];
#pragma unroll
  for (int i = 0; i < 4; ++i)
#pragma unroll
    for (int j = 0; j < 4; ++j) acc[i][j] = 0.f;

  const float* Apt = A + (size_t)(bm + lr) * lda + lk;
  const float* Bpt = B + (size_t)(bn + lr) * ldb + lk;
  const bool bv = (bn + lr) < N;

  for (int k0 = 0; k0 < K; k0 += 16) {
    float4 a4 = *(const float4*)(Apt + k0);
    float4 b4 = bv ? *(const float4*)(Bpt + k0) : make_float4(0.f, 0.f, 0.f, 0.f);
    __syncthreads();
    As[lk + 0][lr] = a4.x; As[lk + 1][lr] = a4.y;
    As[lk + 2][lr] = a4.z; As[lk + 3][lr] = a4.w;
    Bs[lk + 0][lr] = b4.x; Bs[lk + 1][lr] = b4.y;
    Bs[lk + 2][lr] = b4.z; Bs[lk + 3][lr] = b4.w;
    __syncthreads();
#pragma unroll
    for (int k = 0; k < 16; ++k) {
      const float4 av = *(const float4*)(&As[k][ty << 2]);
      const float4 bw = *(const float4*)(&Bs[k][tx << 2]);
      float a4r[4] = {av.x, av.y, av.z, av.w};
      float b4r[4] = {bw.x, bw.y, bw.z, bw.w};
#pragma unroll
      for (int i = 0; i < 4; ++i)
#pragma unroll
        for (int j = 0; j < 4; ++j)
          acc[i][j] = fmaf(a4r[i], b4r[j], acc[i][j]);
    }
  }

  const int m = bm + (ty << 2);
  const int n = bn + (tx << 2);
#pragma unroll
  for (int i = 0; i < 4; ++i) {
    float v[4] = {acc[i][0], acc[i][1], acc[i][2], acc[i][3]};
    if (EPI == 1) {
#pragma unroll
      for (int j = 0; j < 4; ++j)
        if (n + j < N) v[j] = softplus_(v[j] + bias[n + j]);
    }
    if (n + 3 < N) {
      *(float4*)(C + (size_t)(m + i) * ldc + n) = make_float4(v[0], v[1], v[2], v[3]);
    } else {
#pragma unroll
      for (int j = 0; j < 4; ++j)
        if (n + j < N) C[(size_t)(m + i) * ldc + n + j] = v[j];
    }
  }
}

// ---------------------------------------------------------------------------
// Channel alignment features (rfft2 16x16 magnitude band ratio). X stride 2048.
// ---------------------------------------------------------------------------
__global__ __launch_bounds__(256) void feat_kernel(
    const float* __restrict__ X, float* __restrict__ features)
{
  __shared__ float xin[256][17];
  __shared__ float Rf[16 * 315];
  __shared__ float tc[16], ts[16];
  __shared__ float part2[16][16][2];

  const int tid = threadIdx.x;
  const int frame = blockIdx.x >> 7;
  const int cg = blockIdx.x & 127;
  const int b = frame >> 3, t = frame & 7;
  const int c0 = cg << 4;

  if (tid < 16) {
    float ang = 0.39269908169872414f * (float)tid;
    tc[tid] = cosf(ang);
    ts[tid] = sinf(ang);
  }
  const float* xb = X + ((size_t)(b * LSEQ + t * 256) << 11) + c0;
  for (int i = tid; i < 256 * 16; i += 256) {
    int hw = i >> 4, ci = i & 15;
    xin[hw][ci] = xb[((size_t)hw << 11) + ci];
  }
  __syncthreads();

  {
    const int ci = tid & 15, h = tid >> 4;
    float re[9], im[9];
#pragma unroll
    for (int kw = 0; kw < 9; ++kw) { re[kw] = 0.f; im[kw] = 0.f; }
#pragma unroll
    for (int w = 0; w < 16; ++w) {
      float x = xin[(h << 4) + w][ci];
#pragma unroll
      for (int kw = 0; kw < 9; ++kw) {
        int ph = (kw * w) & 15;
        re[kw] = fmaf(x, tc[ph], re[kw]);
        im[kw] = fmaf(-x, ts[ph], im[kw]);
      }
    }
#pragma unroll
    for (int kw = 0; kw < 9; ++kw) {
      Rf[ci * 315 + kw * 35 + 2 * h]     = re[kw];
      Rf[ci * 315 + kw * 35 + 2 * h + 1] = im[kw];
    }
  }
  __syncthreads();

  {
    const int ci = tid & 15, kh = tid >> 4;
    float ut = 0.f, tt = 0.f;
    for (int kw = 0; kw < 9; ++kw) {
      float fre = 0.f, fim = 0.f;
#pragma unroll
      for (int h = 0; h < 16; ++h) {
        int ph = (kh * h) & 15;
        float c = tc[ph], s = ts[ph];
        float rr = Rf[ci * 315 + kw * 35 + 2 * h];
        float ri = Rf[ci * 315 + kw * 35 + 2 * h + 1];
        fre += rr * c + ri * s;
        fim += ri * c - rr * s;
      }
      float mag = sqrtf(fre * fre + fim * fim + 1e-8f);
      int sh = (kh + 8) & 15;
      int sw2 = kw + 4; if (sw2 >= 9) sw2 -= 9;
      float dh = (float)(sh - 8) / 16.0f;
      float dw = (float)(sw2 - 4) / 9.0f;
      tt += mag;
      if (dh * dh + dw * dw >= 0.25f) ut += mag;
    }
    part2[ci][kh][0] = ut;
    part2[ci][kh][1] = tt;
  }
  __syncthreads();

  if (tid < 16) {
    float ut = 0.f, tt = 0.f;
    for (int kh = 0; kh < 16; ++kh) { ut += part2[tid][kh][0]; tt += part2[tid][kh][1]; }
    features[frame * DI + c0 + tid] = ut / (tt + 1e-8f);
  }
}

// ---------------------------------------------------------------------------
// loss + norms + softmax(mean feat) + attention + A_max/A_min + A out. 1 block.
// ---------------------------------------------------------------------------
__global__ __launch_bounds__(256) void alpha_kernel(
    const float* __restrict__ feats, const float* __restrict__ A_log,
    float* __restrict__ Aws, float* __restrict__ loss_out)
{
  __shared__ float red[256];
  __shared__ float invn[32];
  __shared__ float PT[32][257];
  __shared__ float AM[256][17];
  __shared__ float sAmax[16], sAmin[16];
  const int tid = threadIdx.x;

  float pn[32];
#pragma unroll
  for (int i = 0; i < 32; ++i) pn[i] = 0.f;
  float md[8];
#pragma unroll
  for (int j = 0; j < 8; ++j) md[j] = 0.f;
  for (int i = 0; i < 32; ++i) {
#pragma unroll
    for (int j = 0; j < 8; ++j) {
      float v = feats[(i << 11) + tid + (j << 8)];
      pn[i] = fmaf(v, v, pn[i]);
      md[j] += v;
    }
  }
#pragma unroll
  for (int j = 0; j < 8; ++j) md[j] *= (1.f / 32.f);
#pragma unroll
  for (int i = 0; i < 32; ++i) PT[i][tid] = pn[i];
  __syncthreads();
  if (tid < 32) {
    float s = 0.f;
    for (int k = 0; k < 256; ++k) s += PT[tid][k];
    invn[tid] = 1.f / fmaxf(sqrtf(s), 1e-12f);
  }
  __syncthreads();

  float gsq = 0.f;
#pragma unroll
  for (int j = 0; j < 8; ++j) {
    float gd = 0.f;
    for (int i = 0; i < 32; ++i)
      gd = fmaf(feats[(i << 11) + tid + (j << 8)], invn[i], gd);
    gsq = fmaf(gd, gd, gsq);
  }
  red[tid] = gsq; __syncthreads();
  for (int s = 128; s > 0; s >>= 1) { if (tid < s) red[tid] += red[tid + s]; __syncthreads(); }
  if (tid == 0) loss_out[0] = 1.f - red[0] * (1.f / 1024.f);
  __syncthreads();

  float lm = md[0];
#pragma unroll
  for (int j = 1; j < 8; ++j) lm = fmaxf(lm, md[j]);
  red[tid] = lm; __syncthreads();
  for (int s = 128; s > 0; s >>= 1) { if (tid < s) red[tid] = fmaxf(red[tid], red[tid + s]); __syncthreads(); }
  const float mmax = red[0]; __syncthreads();

  float p[8]; float ps = 0.f;
#pragma unroll
  for (int j = 0; j < 8; ++j) { p[j] = __expf(md[j] - mmax); ps += p[j]; }
  red[tid] = ps; __syncthreads();
  for (int s = 128; s > 0; s >>= 1) { if (tid < s) red[tid] += red[tid + s]; __syncthreads(); }
  const float psum = red[0]; __syncthreads();

  float amaxl[16], aminl[16], rn[8];
#pragma unroll
  for (int n = 0; n < 16; ++n) { amaxl[n] = -1e30f; aminl[n] = 1e30f; }
#pragma unroll
  for (int j = 0; j < 8; ++j) {
    const int d = tid + (j << 8);
    float ss = 0.f;
#pragma unroll
    for (int n = 0; n < 16; ++n) {
      float a = A_log[(d << 4) + n];
      float e = __expf(a);
      ss = fmaf(e, e, ss);
      amaxl[n] = fmaxf(amaxl[n], a);
      aminl[n] = fminf(aminl[n], a);
    }
    rn[j] = sqrtf(ss);
  }
  float rm = rn[0];
#pragma unroll
  for (int j = 1; j < 8; ++j) rm = fmaxf(rm, rn[j]);
  red[tid] = rm; __syncthreads();
  for (int s = 128; s > 0; s >>= 1) { if (tid < s) red[tid] = fmaxf(red[tid], red[tid + s]); __syncthreads(); }
  const float rnmax = red[0]; __syncthreads();

#pragma unroll
  for (int n = 0; n < 16; ++n) AM[tid][n] = amaxl[n];
  __syncthreads();
  if (tid < 16) { float m = -1e30f; for (int i = 0; i < 256; ++i) m = fmaxf(m, AM[i][tid]); sAmax[tid] = m; }
  __syncthreads();
#pragma unroll
  for (int n = 0; n < 16; ++n) AM[tid][n] = aminl[n];
  __syncthreads();
  if (tid < 16) { float m = 1e30f; for (int i = 0; i < 256; ++i) m = fminf(m, AM[i][tid]); sAmin[tid] = m; }
  __syncthreads();

  const float irn = 1.f / (rnmax + 1e-8f);
#pragma unroll
  for (int j = 0; j < 8; ++j) {
    const int d = tid + (j << 8);
    const float att = rn[j] * irn;
    const float f = p[j] / psum;
    const float alpha = fminf(fmaxf(f * (1.f - att), 0.f), 1.f);
#pragma unroll
    for (int n = 0; n < 16; ++n) {
      float a = A_log[(d << 4) + n];
      float fl = sAmax[n] + sAmin[n] - a;
      float an = (1.f - alpha) * a + alpha * fl;
      Aws[(d << 4) + n] = -__expf(an);
    }
  }
}

// ---------------------------------------------------------------------------
// Depthwise causal conv (k=4) + bias + SiLU, float4 per thread.
// X (b,l,2048) -> U (b,l,2048)
// ---------------------------------------------------------------------------
__global__ __launch_bounds__(256) void conv_kernel(
    const float* __restrict__ X, const float* __restrict__ cw,
    const float* __restrict__ cb, float* __restrict__ U)
{
  const size_t i4 = ((size_t)blockIdx.x << 8) + threadIdx.x;  // < 4,194,304
  const int e4 = (int)(i4 & 511);
  const size_t row = i4 >> 9;          // b*2048 + l
  const int l = (int)(row & 2047);
  const float* xr = X + (row << 11) + (e4 << 2);
  const float4 z4 = make_float4(0.f, 0.f, 0.f, 0.f);
  float4 x0 = *(const float4*)xr;
  float4 x1 = (l >= 1) ? *(const float4*)(xr - 2048) : z4;
  float4 x2 = (l >= 2) ? *(const float4*)(xr - 4096) : z4;
  float4 x3 = (l >= 3) ? *(const float4*)(xr - 6144) : z4;
  const float4* cwf = (const float4*)cw;
  float4 bi = *(const float4*)(cb + (e4 << 2));
  float x0a[4] = {x0.x, x0.y, x0.z, x0.w};
  float x1a[4] = {x1.x, x1.y, x1.z, x1.w};
  float x2a[4] = {x2.x, x2.y, x2.z, x2.w};
  float x3a[4] = {x3.x, x3.y, x3.z, x3.w};
  float bia[4] = {bi.x, bi.y, bi.z, bi.w};
  float o[4];
#pragma unroll
  for (int c = 0; c < 4; ++c) {
    float4 w = cwf[(e4 << 2) + c];
    float acc = bia[c];
    acc = fmaf(x3a[c], w.x, acc);
    acc = fmaf(x2a[c], w.y, acc);
    acc = fmaf(x1a[c], w.z, acc);
    acc = fmaf(x0a[c], w.w, acc);
    o[c] = silu_(acc);
  }
  *(float4*)(U + (i4 << 2)) = make_float4(o[0], o[1], o[2], o[3]);
}

// ---------------------------------------------------------------------------
// Chunked selective scan (delta in X region stride 2048, z in Z stride 2048).
// ---------------------------------------------------------------------------
__global__ __launch_bounds__(256) void scan_pass1(
    const float* __restrict__ delta, const float* __restrict__ U,
    const float* __restrict__ xdbl, const float* __restrict__ Aws,
    float* __restrict__ cs, float* __restrict__ sdt)
{
  __shared__ float blds[CL * 16];
  const int tid = threadIdx.x;
  const int dg = blockIdx.x & 7;
  const int chunk = (blockIdx.x >> 3) & 31;
  const int b = blockIdx.x >> 8;
  const int d = (dg << 8) | tid;
  const int l0 = chunk * CL;

  for (int i = tid; i < CL * 16; i += 256) {
    int l = i >> 4, j = i & 15;
    blds[i] = xdbl[(size_t)(b * LSEQ + l0 + l) * 96 + 64 + j];
  }
  __syncthreads();

  float Ar[16];
#pragma unroll
  for (int n = 0; n < 16; ++n) Ar[n] = Aws[(d << 4) + n];
  float s[16];
#pragma unroll
  for (int n = 0; n < 16; ++n) s[n] = 0.f;
  float sumdt = 0.f;

  const float* dp = delta + ((size_t)b << 22) + ((size_t)l0 << 11) + d;
  const float* up = U + ((size_t)b << 22) + ((size_t)l0 << 11) + d;

  for (int l = 0; l < CL; ++l) {
    const float dt = dp[(size_t)l << 11];
    const float u = up[(size_t)l << 11];
    sumdt += dt;
    const float du = dt * u;
    const float* bl = &blds[l << 4];
#pragma unroll
    for (int n = 0; n < 16; ++n)
      s[n] = fmaf(s[n], __expf(dt * Ar[n]), du * bl[n]);
  }

  float* csp = cs + ((((size_t)b * NC + chunk) * 2048 + d) << 4);
#pragma unroll
  for (int n = 0; n < 4; ++n)
    *(float4*)(csp + (n << 2)) = make_float4(s[4*n], s[4*n+1], s[4*n+2], s[4*n+3]);
  sdt[((size_t)b * NC + chunk) * 2048 + d] = sumdt;
}

__global__ __launch_bounds__(256) void scan_mid(
    float* __restrict__ cs, const float* __restrict__ sdt,
    const float* __restrict__ Aws)
{
  const int b = blockIdx.x >> 3;
  const int d = ((blockIdx.x & 7) << 8) | threadIdx.x;
  float Ar[16];
#pragma unroll
  for (int n = 0; n < 16; ++n) Ar[n] = Aws[(d << 4) + n];
  float si[16];
#pragma unroll
  for (int n = 0; n < 16; ++n) si[n] = 0.f;

  for (int c = 0; c < NC; ++c) {
    const size_t base = ((size_t)b * NC + c) * 2048 + d;
    float* csp = cs + (base << 4);
    float sl[16];
#pragma unroll
    for (int n = 0; n < 4; ++n) {
      float4 v = *(const float4*)(csp + (n << 2));
      sl[4*n] = v.x; sl[4*n+1] = v.y; sl[4*n+2] = v.z; sl[4*n+3] = v.w;
    }
    const float sm = sdt[base];
#pragma unroll
    for (int n = 0; n < 4; ++n)
      *(float4*)(csp + (n << 2)) = make_float4(si[4*n], si[4*n+1], si[4*n+2], si[4*n+3]);
#pragma unroll
    for (int n = 0; n < 16; ++n)
      si[n] = fmaf(si[n], __expf(sm * Ar[n]), sl[n]);
  }
}

__global__ __launch_bounds__(256) void scan_pass3(
    const float* __restrict__ delta, const float* __restrict__ Z,
    float* __restrict__ U,
    const float* __restrict__ xdbl, const float* __restrict__ Aws,
    const float* __restrict__ Dp, const float* __restrict__ cs)
{
  __shared__ float bclds[CL * 32];
  const int tid = threadIdx.x;
  const int dg = blockIdx.x & 7;
  const int chunk = (blockIdx.x >> 3) & 31;
  const int b = blockIdx.x >> 8;
  const int d = (dg << 8) | tid;
  const int l0 = chunk * CL;

  for (int i = tid; i < CL * 32; i += 256) {
    int l = i >> 5, j = i & 31;
    bclds[i] = xdbl[(size_t)(b * LSEQ + l0 + l) * 96 + 64 + j];
  }
  __syncthreads();

  float Ar[16];
#pragma unroll
  for (int n = 0; n < 16; ++n) Ar[n] = Aws[(d << 4) + n];
  const float Dd = Dp[d];

  const float* csp = cs + ((((size_t)b * NC + chunk) * 2048 + d) << 4);
  float s[16];
#pragma unroll
  for (int n = 0; n < 4; ++n) {
    float4 v = *(const float4*)(csp + (n << 2));
    s[4*n] = v.x; s[4*n+1] = v.y; s[4*n+2] = v.z; s[4*n+3] = v.w;
  }

  const float* dp = delta + ((size_t)b << 22) + ((size_t)l0 << 11) + d;
  const float* zp = Z + ((size_t)b << 22) + ((size_t)l0 << 11) + d;
  float* up = U + ((size_t)b << 22) + ((size_t)l0 << 11) + d;

  for (int l = 0; l < CL; ++l) {
    const float dt = dp[(size_t)l << 11];
    const float u = up[(size_t)l << 11];
    const float z = zp[(size_t)l << 11];
    const float du = dt * u;
    const float* bcl = &bclds[l << 5];
    float y = 0.f;
#pragma unroll
    for (int n = 0; n < 16; ++n) {
      s[n] = fmaf(s[n], __expf(dt * Ar[n]), du * bcl[n]);
      y = fmaf(s[n], bcl[16 + n], y);
    }
    const float yv = fmaf(u, Dd, y);
    up[(size_t)l << 11] = yv * silu_(z);
  }
}

// ---------------------------------------------------------------------------
extern "C" void kernel_launch(void* const* d_in, const int* in_sizes, int n_in,
                              void* d_out, int out_size, void* d_ws, size_t ws_size,
                              hipStream_t stream)
{
  const float* hs         = (const float*)d_in[0];
  const float* in_proj_w  = (const float*)d_in[4];
  const float* conv_w     = (const float*)d_in[5];
  const float* conv_b     = (const float*)d_in[6];
  const float* x_proj_w   = (const float*)d_in[7];
  const float* dt_proj_w  = (const float*)d_in[8];
  const float* dt_proj_b  = (const float*)d_in[9];
  const float* A_log      = (const float*)d_in[10];
  const float* Dp         = (const float*)d_in[11];
  const float* out_proj_w = (const float*)d_in[12];
  float* out = (float*)d_out;
  float* ws = (float*)d_ws;

  float* X     = ws + OFF_X;
  float* Z     = ws + OFF_Z;
  float* U     = ws + OFF_U;
  float* cs    = ws + OFF_CS;
  float* sdt   = ws + OFF_SDT;
  float* xdbl  = ws + OFF_XDBL;
  float* feats = ws + OFF_FEAT;
  float* Aws   = ws + OFF_AWS;
  unsigned short* A1s = (unsigned short*)(ws + OFF_S);
  unsigned short* B1s = (unsigned short*)(ws + OFF_B1);
  unsigned short* B2s = (unsigned short*)(ws + OFF_B1);

  const dim3 blk(256);

  // 0. split hs (2,097,152 float4s) + in_proj_w (1,048,576 float4s)
  split2_w<<<12288, blk, 0, stream>>>(hs, A1s, 10, (size_t)2097152,
                                      in_proj_w, B1s, 10);
  // 1. xz = hs @ in_proj_w^T  (MFMA split, M=8192,N=4096,K=1024) -> X | Z
  //    Z columns (bn>=2048) use hi*hi only (1 MFMA pass) — silu-gate budget.
  gemm_mfma<1, 0><<<dim3(32, 64), blk, 0, stream>>>(A1s, B1s, X, Z, 1024, 2048, 2, 2048);
  // 2. channel-alignment features (reads X)
  feat_kernel<<<4096, blk, 0, stream>>>(X, feats);
  // 3. depthwise conv + silu (X -> U)
  conv_kernel<<<16384, blk, 0, stream>>>(X, conv_w, conv_b, U);
  // 3b. split out_proj_w (524,288 float4s) -> 2048 blocks (overlays dead B1s)
  split2_w<<<2048, blk, 0, stream>>>(out_proj_w, B2s, 11, (size_t)524288,
                                     out_proj_w, B2s, 11);
  // 4. loss + norms + alpha + A
  alpha_kernel<<<1, blk, 0, stream>>>(feats, A_log, Aws, out + 8388608);
  // 5. x_dbl = U @ x_proj_w^T   (M=8192, N=96, K=2048)
  gemm_nt<0><<<dim3(2, 128), blk, 0, stream>>>(U, DI, x_proj_w, DI, xdbl, 96, 96, DI, nullptr);
  // 6. delta = softplus(x_dbl[:, :64] @ dt_proj_w^T + b) -> X region (dead x)
  gemm_nt<1><<<dim3(32, 128), blk, 0, stream>>>(xdbl, 96, dt_proj_w, 64, X, DI, DI, 64, dt_proj_b);
  // 7. chunked selective scan; y overwrites U (fp32, stays fp32)
  scan_pass1<<<1024, blk, 0, stream>>>(X, U, xdbl, Aws, cs, sdt);
  scan_mid<<<32, blk, 0, stream>>>(cs, sdt, Aws);
  scan_pass3<<<1024, blk, 0, stream>>>(X, Z, U, xdbl, Aws, Dp, cs);
  // 8. out = y @ out_proj_w^T  (MFMA, A=fp32 y split in-register during staging)
  gemm_mfma<0, 1><<<dim3(8, 64), blk, 0, stream>>>(U, B2s, out, nullptr, 2048, 1024, 0, 1 << 30);
}

// Round 9
// 921.118 us; speedup vs baseline: 1.1417x; 1.1417x over previous
//
#include <hip/hip_runtime.h>
#include <math.h>
#include <stdint.h>

// Problem constants (fixed instance)
#define LSEQ 2048
#define DM   1024
#define DI   2048
#define NC   32     // scan chunks per sequence
#define CL   64     // scan chunk length (NC*CL == LSEQ)

// ---------------------------------------------------------------------------
// Workspace layout (float units). Total 62,914,560 floats = 251.7 MB.
//  X  [0,          16777216)  : x half of in_proj output; later delta (in place)
//  Z  [16777216,   33554432)  : z half
//  U  [33554432,   50331648)  : conv output u -> y (in place, stays fp32)
//  S  [50331648,   58720256)  : A1' (hs split bf16) until gemm1 done, then
//                               cs(+xdbl split-K partials)/sdt/xdbl/feats/Aws
//  B1 [58720256,   62914560)  : B1' (in_proj split) -> B2' (out_proj split)
// ---------------------------------------------------------------------------
#define OFF_X     ((size_t)0)
#define OFF_Z     ((size_t)16777216)
#define OFF_U     ((size_t)33554432)
#define OFF_S     ((size_t)50331648)
#define OFF_CS    (OFF_S)                      // 4,194,304 floats (also xdbl partials)
#define OFF_SDT   (OFF_S + 4194304)            //   262,144
#define OFF_XDBL  (OFF_S + 4456448)            //   786,432
#define OFF_FEAT  (OFF_S + 5242880)            //    65,536
#define OFF_AWS   (OFF_S + 5308448)            //    32,768
#define OFF_B1    ((size_t)58720256)

__device__ __forceinline__ float silu_(float x) { return x / (1.f + __expf(-x)); }
__device__ __forceinline__ float softplus_(float x) {
  return fmaxf(x, 0.f) + log1pf(__expf(-fabsf(x)));
}
__device__ __forceinline__ unsigned short f2bf(float x) {
  unsigned int u = __float_as_uint(x);
  u += 0x7fffu + ((u >> 16) & 1u);      // RNE (inputs finite)
  return (unsigned short)(u >> 16);
}
__device__ __forceinline__ float bf2f(unsigned short h) {
  return __uint_as_float(((unsigned int)h) << 16);
}

typedef __attribute__((ext_vector_type(8))) short bf16x8;
typedef __attribute__((ext_vector_type(4))) float f32x4;

__device__ __forceinline__ void gl2lds16(const void* g, void* l) {
  __builtin_amdgcn_global_load_lds(
      (const __attribute__((address_space(1))) unsigned int*)(uintptr_t)g,
      (__attribute__((address_space(3))) unsigned int*)(uintptr_t)l,
      16, 0, 0);
}

// ---------------------------------------------------------------------------
// Split fp32 -> [hi | lo] bf16 per row, two tensors in one dispatch.
// Each thread handles ONE float4. Tensor a = first na4 float4-slots.
// ---------------------------------------------------------------------------
__global__ __launch_bounds__(256) void split2_w(
    const float* __restrict__ a, unsigned short* __restrict__ oa, int ksa,
    size_t na4,
    const float* __restrict__ b, unsigned short* __restrict__ ob, int ksb)
{
  size_t i4 = ((size_t)blockIdx.x << 8) + threadIdx.x;
  const float* src; unsigned short* dst; int ks;
  if (i4 < na4) { src = a; dst = oa; ks = ksa; }
  else          { src = b; dst = ob; ks = ksb; i4 -= na4; }
  const size_t flat = i4 << 2;
  const int K = 1 << ks;
  const size_t row = flat >> ks;
  const int k = (int)(flat & (size_t)(K - 1));
  float4 v = *(const float4*)(src + flat);
  float f[4] = {v.x, v.y, v.z, v.w};
  unsigned short h[4], lo[4];
#pragma unroll
  for (int c = 0; c < 4; ++c) { h[c] = f2bf(f[c]); lo[c] = f2bf(f[c] - bf2f(h[c])); }
  unsigned short* o = dst + (row << (ks + 1)) + k;
  *(uint2*)(o)     = make_uint2((unsigned)h[0]  | ((unsigned)h[1]  << 16),
                                (unsigned)h[2]  | ((unsigned)h[3]  << 16));
  *(uint2*)(o + K) = make_uint2((unsigned)lo[0] | ((unsigned)lo[1] << 16),
                                (unsigned)lo[2] | ((unsigned)lo[3] << 16));
}

// ---------------------------------------------------------------------------
// Split-bf16 MFMA GEMM: C[M,N] = A·B^T.
// NPASS=3: fp32-class via a_hi·b_hi + a_hi·b_lo + a_lo·b_hi (48 MFMA/k0).
// NPASS=1: hi·hi only (16 MFMA/k0, lo LDS compiled out) — silu-gate budget.
// A_FP32: A is fp32 [M][K], hi/lo split in-register during staging.
// Else A is bf16 [M][2K] [hi|lo]. B always bf16 [N][2K] [hi|lo].
// 128x128 tile, 4 waves, BK=32, 16x16x32 MFMA, XOR bank swizzle on LDS.
// Block swizzle: lin%8 = XCD; n-index = ((t&nmask)<<3)|xcd; walk m per XCD.
// ---------------------------------------------------------------------------
template <int NPASS, int A_FP32>
__global__ __launch_bounds__(256) void gemm_mfma(
    const void* __restrict__ Avp, const unsigned short* __restrict__ Bp,
    float* __restrict__ C, int K, int ldc, int nxs)
{
  __shared__ unsigned short AsH[128 * 32];
  __shared__ unsigned short BsH[128 * 32];
  __shared__ unsigned short AsL[(NPASS > 1) ? 128 * 32 : 8];
  __shared__ unsigned short BsL[(NPASS > 1) ? 128 * 32 : 8];
  const int tid = threadIdx.x;
  const int lin = blockIdx.y * gridDim.x + blockIdx.x;
  const int xcd = lin & 7;
  const int t = lin >> 3;
  const int nmask = (1 << nxs) - 1;
  const int bn = (((t & nmask) << 3) | xcd) << 7;
  const int bm = (t >> nxs) << 7;
  const int K2 = K * 2;

  const int wave = tid >> 6, lane = tid & 63;
  const int wm = (wave >> 1) << 6, wn = (wave & 1) << 6;
  const int lm = lane & 15, quad = lane >> 4;
  const int sw = (lm >> 1) & 3;        // reader swizzle (row>>1)&3 == (lm>>1)&3

  f32x4 acc[4][4] = {};

  // staging: thread tid fills LDS slots tid (rows 0..63) and tid+256
  // (rows 64..127); slot s=(r,q) takes global k-chunk q^((r>>1)&3).
  const int r0 = tid >> 2;
  const int kq = ((tid & 3) ^ ((r0 >> 1) & 3)) << 3;   // element offset
  const unsigned short* BgH0 = Bp + (size_t)(bn + r0) * K2 + kq;
  const unsigned short* BgH1 = Bp + (size_t)(bn + 64 + r0) * K2 + kq;
  unsigned short* lA0 = &AsH[(size_t)tid * 8];
  unsigned short* lA1 = &AsH[(size_t)(256 + tid) * 8];
  unsigned short* lB0 = &BsH[(size_t)tid * 8];
  unsigned short* lB1 = &BsH[(size_t)(256 + tid) * 8];
  unsigned short* lAl0 = (NPASS > 1) ? &AsL[(size_t)tid * 8] : nullptr;
  unsigned short* lAl1 = (NPASS > 1) ? &AsL[(size_t)(256 + tid) * 8] : nullptr;
  unsigned short* lBl0 = (NPASS > 1) ? &BsL[(size_t)tid * 8] : nullptr;
  unsigned short* lBl1 = (NPASS > 1) ? &BsL[(size_t)(256 + tid) * 8] : nullptr;

  const unsigned short* AgH0 = nullptr; const unsigned short* AgH1 = nullptr;
  const float* Af0 = nullptr; const float* Af1 = nullptr;
  if (A_FP32) {
    const float* Af = (const float*)Avp;
    Af0 = Af + (size_t)(bm + r0) * K + kq;
    Af1 = Af + (size_t)(bm + 64 + r0) * K + kq;
  } else {
    const unsigned short* Ab = (const unsigned short*)Avp;
    AgH0 = Ab + (size_t)(bm + r0) * K2 + kq;
    AgH1 = Ab + (size_t)(bm + 64 + r0) * K2 + kq;
  }

  for (int k0 = 0; k0 < K; k0 += 32) {
    __syncthreads();
    if (A_FP32) {
      float4 u0 = *(const float4*)(Af0 + k0);
      float4 u1 = *(const float4*)(Af0 + k0 + 4);
      float4 v0 = *(const float4*)(Af1 + k0);
      float4 v1 = *(const float4*)(Af1 + k0 + 4);
      float fu[8] = {u0.x,u0.y,u0.z,u0.w,u1.x,u1.y,u1.z,u1.w};
      float fv[8] = {v0.x,v0.y,v0.z,v0.w,v1.x,v1.y,v1.z,v1.w};
      unsigned int hu[4], lu[4], hv[4], lv[4];
#pragma unroll
      for (int c = 0; c < 4; ++c) {
        unsigned short h0 = f2bf(fu[2*c]),   l0 = f2bf(fu[2*c]   - bf2f(h0));
        unsigned short h1 = f2bf(fu[2*c+1]), l1 = f2bf(fu[2*c+1] - bf2f(h1));
        hu[c] = (unsigned)h0 | ((unsigned)h1 << 16);
        lu[c] = (unsigned)l0 | ((unsigned)l1 << 16);
        unsigned short g0 = f2bf(fv[2*c]),   m0 = f2bf(fv[2*c]   - bf2f(g0));
        unsigned short g1 = f2bf(fv[2*c+1]), m1 = f2bf(fv[2*c+1] - bf2f(g1));
        hv[c] = (unsigned)g0 | ((unsigned)g1 << 16);
        lv[c] = (unsigned)m0 | ((unsigned)m1 << 16);
      }
      *(uint4*)lA0  = make_uint4(hu[0], hu[1], hu[2], hu[3]);
      *(uint4*)lA1  = make_uint4(hv[0], hv[1], hv[2], hv[3]);
      if (NPASS > 1) {
        *(uint4*)lAl0 = make_uint4(lu[0], lu[1], lu[2], lu[3]);
        *(uint4*)lAl1 = make_uint4(lv[0], lv[1], lv[2], lv[3]);
      }
    } else {
      gl2lds16(AgH0 + k0, lA0);
      gl2lds16(AgH1 + k0, lA1);
      if (NPASS > 1) {
        gl2lds16(AgH0 + K + k0, lAl0);
        gl2lds16(AgH1 + K + k0, lAl1);
      }
    }
    gl2lds16(BgH0 + k0, lB0);
    gl2lds16(BgH1 + k0, lB1);
    if (NPASS > 1) {
      gl2lds16(BgH0 + K + k0, lBl0);
      gl2lds16(BgH1 + K + k0, lBl1);
    }
    __syncthreads();

    bf16x8 aH[4], bH[4];
#pragma unroll
    for (int i = 0; i < 4; ++i)
      aH[i] = *(const bf16x8*)&AsH[(wm + i * 16 + lm) * 32 + ((quad ^ sw) << 3)];
#pragma unroll
    for (int j = 0; j < 4; ++j)
      bH[j] = *(const bf16x8*)&BsH[(wn + j * 16 + lm) * 32 + ((quad ^ sw) << 3)];
#pragma unroll
    for (int i = 0; i < 4; ++i)
#pragma unroll
      for (int j = 0; j < 4; ++j)
        acc[i][j] = __builtin_amdgcn_mfma_f32_16x16x32_bf16(aH[i], bH[j], acc[i][j], 0, 0, 0);
    if (NPASS > 1) {
      bf16x8 aL[4], bL[4];
#pragma unroll
      for (int i = 0; i < 4; ++i)
        aL[i] = *(const bf16x8*)&AsL[(wm + i * 16 + lm) * 32 + ((quad ^ sw) << 3)];
#pragma unroll
      for (int j = 0; j < 4; ++j)
        bL[j] = *(const bf16x8*)&BsL[(wn + j * 16 + lm) * 32 + ((quad ^ sw) << 3)];
#pragma unroll
      for (int i = 0; i < 4; ++i)
#pragma unroll
        for (int j = 0; j < 4; ++j) {
          acc[i][j] = __builtin_amdgcn_mfma_f32_16x16x32_bf16(aH[i], bL[j], acc[i][j], 0, 0, 0);
          acc[i][j] = __builtin_amdgcn_mfma_f32_16x16x32_bf16(aL[i], bH[j], acc[i][j], 0, 0, 0);
        }
    }
  }

  // epilogue: C/D layout col=lane&15 (n, from B), row=quad*4+reg (m, from A)
#pragma unroll
  for (int i = 0; i < 4; ++i) {
    const int m = bm + wm + i * 16 + quad * 4;
#pragma unroll
    for (int j = 0; j < 4; ++j) {
      const int n = bn + wn + j * 16 + lm;
#pragma unroll
      for (int r = 0; r < 4; ++r)
        C[(size_t)(m + r) * ldc + n] = acc[i][j][r];
    }
  }
}

// ---------------------------------------------------------------------------
// fp32 NT GEMM (small shapes): C[M,N] = A[M,K]·B[N,K]^T. 64x64 tile, BK=16.
// EPI: 0 none, 1 softplus(acc + bias[n]). Split-K via blockIdx.z: segment z
// reads k-window [z*K, (z+1)*K) and writes C + z*cseg.
// ---------------------------------------------------------------------------
template <int EPI>
__global__ __launch_bounds__(256) void gemm_nt(
    const float* __restrict__ A, int lda,
    const float* __restrict__ B, int ldb,
    float* __restrict__ C, int ldc,
    int N, int K, const float* __restrict__ bias, size_t cseg)
{
  __shared__ float As[16][68];
  __shared__ float Bs[16][68];
  const int tid = threadIdx.x;
  const int bm = blockIdx.y << 6;
  const int bn = blockIdx.x << 6;
  const int kz = blockIdx.z;
  A += (size_t)kz * K;
  B += (size_t)kz * K;
  C += (size_t)kz * cseg;
  const int lr = tid >> 2;
  const int lk = (tid & 3) << 2;
  const int tx = tid & 15, ty = tid >> 4;

  float acc[4][4];
#pragma unroll
  for (int i = 0; i < 4; ++i)
#pragma unroll
    for (int j = 0; j < 4; ++j) acc[i][j] = 0.f;

  const float* Apt = A + (size_t)(bm + lr) * lda + lk;
  const float* Bpt = B + (size_t)(bn + lr) * ldb + lk;
  const bool bv = (bn + lr) < N;

  for (int k0 = 0; k0 < K; k0 += 16) {
    float4 a4 = *(const float4*)(Apt + k0);
    float4 b4 = bv ? *(const float4*)(Bpt + k0) : make_float4(0.f, 0.f, 0.f, 0.f);
    __syncthreads();
    As[lk + 0][lr] = a4.x; As[lk + 1][lr] = a4.y;
    As[lk + 2][lr] = a4.z; As[lk + 3][lr] = a4.w;
    Bs[lk + 0][lr] = b4.x; Bs[lk + 1][lr] = b4.y;
    Bs[lk + 2][lr] = b4.z; Bs[lk + 3][lr] = b4.w;
    __syncthreads();
#pragma unroll
    for (int k = 0; k < 16; ++k) {
      const float4 av = *(const float4*)(&As[k][ty << 2]);
      const float4 bw = *(const float4*)(&Bs[k][tx << 2]);
      float a4r[4] = {av.x, av.y, av.z, av.w};
      float b4r[4] = {bw.x, bw.y, bw.z, bw.w};
#pragma unroll
      for (int i = 0; i < 4; ++i)
#pragma unroll
        for (int j = 0; j < 4; ++j)
          acc[i][j] = fmaf(a4r[i], b4r[j], acc[i][j]);
    }
  }

  const int m = bm + (ty << 2);
  const int n = bn + (tx << 2);
#pragma unroll
  for (int i = 0; i < 4; ++i) {
    float v[4] = {acc[i][0], acc[i][1], acc[i][2], acc[i][3]};
    if (EPI == 1) {
#pragma unroll
      for (int j = 0; j < 4; ++j)
        if (n + j < N) v[j] = softplus_(v[j] + bias[n + j]);
    }
    if (n + 3 < N) {
      *(float4*)(C + (size_t)(m + i) * ldc + n) = make_float4(v[0], v[1], v[2], v[3]);
    } else {
#pragma unroll
      for (int j = 0; j < 4; ++j)
        if (n + j < N) C[(size_t)(m + i) * ldc + n + j] = v[j];
    }
  }
}

// ---------------------------------------------------------------------------
// 4-way split-K reduce: O[i] = sum_z P[z*seg + i], over n4 float4s.
// ---------------------------------------------------------------------------
__global__ __launch_bounds__(256) void reduce4(
    const float* __restrict__ P, float* __restrict__ O, size_t seg)
{
  const size_t i = ((size_t)blockIdx.x << 8) + threadIdx.x;
  float4 a = ((const float4*)P)[i];
  float4 b = ((const float4*)(P + seg))[i];
  float4 c = ((const float4*)(P + 2 * seg))[i];
  float4 d = ((const float4*)(P + 3 * seg))[i];
  ((float4*)O)[i] = make_float4(a.x + b.x + c.x + d.x,
                                a.y + b.y + c.y + d.y,
                                a.z + b.z + c.z + d.z,
                                a.w + b.w + c.w + d.w);
}

// ---------------------------------------------------------------------------
// Channel alignment features (rfft2 16x16 magnitude band ratio). X stride 2048.
// ---------------------------------------------------------------------------
__global__ __launch_bounds__(256) void feat_kernel(
    const float* __restrict__ X, float* __restrict__ features)
{
  __shared__ float xin[256][17];
  __shared__ float Rf[16 * 315];
  __shared__ float tc[16], ts[16];
  __shared__ float part2[16][16][2];

  const int tid = threadIdx.x;
  const int frame = blockIdx.x >> 7;
  const int cg = blockIdx.x & 127;
  const int b = frame >> 3, t = frame & 7;
  const int c0 = cg << 4;

  if (tid < 16) {
    float ang = 0.39269908169872414f * (float)tid;
    tc[tid] = cosf(ang);
    ts[tid] = sinf(ang);
  }
  const float* xb = X + ((size_t)(b * LSEQ + t * 256) << 11) + c0;
  for (int i = tid; i < 256 * 16; i += 256) {
    int hw = i >> 4, ci = i & 15;
    xin[hw][ci] = xb[((size_t)hw << 11) + ci];
  }
  __syncthreads();

  {
    const int ci = tid & 15, h = tid >> 4;
    float re[9], im[9];
#pragma unroll
    for (int kw = 0; kw < 9; ++kw) { re[kw] = 0.f; im[kw] = 0.f; }
#pragma unroll
    for (int w = 0; w < 16; ++w) {
      float x = xin[(h << 4) + w][ci];
#pragma unroll
      for (int kw = 0; kw < 9; ++kw) {
        int ph = (kw * w) & 15;
        re[kw] = fmaf(x, tc[ph], re[kw]);
        im[kw] = fmaf(-x, ts[ph], im[kw]);
      }
    }
#pragma unroll
    for (int kw = 0; kw < 9; ++kw) {
      Rf[ci * 315 + kw * 35 + 2 * h]     = re[kw];
      Rf[ci * 315 + kw * 35 + 2 * h + 1] = im[kw];
    }
  }
  __syncthreads();

  {
    const int ci = tid & 15, kh = tid >> 4;
    float ut = 0.f, tt = 0.f;
    for (int kw = 0; kw < 9; ++kw) {
      float fre = 0.f, fim = 0.f;
#pragma unroll
      for (int h = 0; h < 16; ++h) {
        int ph = (kh * h) & 15;
        float c = tc[ph], s = ts[ph];
        float rr = Rf[ci * 315 + kw * 35 + 2 * h];
        float ri = Rf[ci * 315 + kw * 35 + 2 * h + 1];
        fre += rr * c + ri * s;
        fim += ri * c - rr * s;
      }
      float mag = sqrtf(fre * fre + fim * fim + 1e-8f);
      int sh = (kh + 8) & 15;
      int sw2 = kw + 4; if (sw2 >= 9) sw2 -= 9;
      float dh = (float)(sh - 8) / 16.0f;
      float dw = (float)(sw2 - 4) / 9.0f;
      tt += mag;
      if (dh * dh + dw * dw >= 0.25f) ut += mag;
    }
    part2[ci][kh][0] = ut;
    part2[ci][kh][1] = tt;
  }
  __syncthreads();

  if (tid < 16) {
    float ut = 0.f, tt = 0.f;
    for (int kh = 0; kh < 16; ++kh) { ut += part2[tid][kh][0]; tt += part2[tid][kh][1]; }
    features[frame * DI + c0 + tid] = ut / (tt + 1e-8f);
  }
}

// ---------------------------------------------------------------------------
// loss + norms + softmax(mean feat) + attention + A_max/A_min + A out. 1 block.
// ---------------------------------------------------------------------------
__global__ __launch_bounds__(256) void alpha_kernel(
    const float* __restrict__ feats, const float* __restrict__ A_log,
    float* __restrict__ Aws, float* __restrict__ loss_out)
{
  __shared__ float red[256];
  __shared__ float invn[32];
  __shared__ float PT[32][257];
  __shared__ float AM[256][17];
  __shared__ float sAmax[16], sAmin[16];
  const int tid = threadIdx.x;

  float pn[32];
#pragma unroll
  for (int i = 0; i < 32; ++i) pn[i] = 0.f;
  float md[8];
#pragma unroll
  for (int j = 0; j < 8; ++j) md[j] = 0.f;
  for (int i = 0; i < 32; ++i) {
#pragma unroll
    for (int j = 0; j < 8; ++j) {
      float v = feats[(i << 11) + tid + (j << 8)];
      pn[i] = fmaf(v, v, pn[i]);
      md[j] += v;
    }
  }
#pragma unroll
  for (int j = 0; j < 8; ++j) md[j] *= (1.f / 32.f);
#pragma unroll
  for (int i = 0; i < 32; ++i) PT[i][tid] = pn[i];
  __syncthreads();
  if (tid < 32) {
    float s = 0.f;
    for (int k = 0; k < 256; ++k) s += PT[tid][k];
    invn[tid] = 1.f / fmaxf(sqrtf(s), 1e-12f);
  }
  __syncthreads();

  float gsq = 0.f;
#pragma unroll
  for (int j = 0; j < 8; ++j) {
    float gd = 0.f;
    for (int i = 0; i < 32; ++i)
      gd = fmaf(feats[(i << 11) + tid + (j << 8)], invn[i], gd);
    gsq = fmaf(gd, gd, gsq);
  }
  red[tid] = gsq; __syncthreads();
  for (int s = 128; s > 0; s >>= 1) { if (tid < s) red[tid] += red[tid + s]; __syncthreads(); }
  if (tid == 0) loss_out[0] = 1.f - red[0] * (1.f / 1024.f);
  __syncthreads();

  float lm = md[0];
#pragma unroll
  for (int j = 1; j < 8; ++j) lm = fmaxf(lm, md[j]);
  red[tid] = lm; __syncthreads();
  for (int s = 128; s > 0; s >>= 1) { if (tid < s) red[tid] = fmaxf(red[tid], red[tid + s]); __syncthreads(); }
  const float mmax = red[0]; __syncthreads();

  float p[8]; float ps = 0.f;
#pragma unroll
  for (int j = 0; j < 8; ++j) { p[j] = __expf(md[j] - mmax); ps += p[j]; }
  red[tid] = ps; __syncthreads();
  for (int s = 128; s > 0; s >>= 1) { if (tid < s) red[tid] += red[tid + s]; __syncthreads(); }
  const float psum = red[0]; __syncthreads();

  float amaxl[16], aminl[16], rn[8];
#pragma unroll
  for (int n = 0; n < 16; ++n) { amaxl[n] = -1e30f; aminl[n] = 1e30f; }
#pragma unroll
  for (int j = 0; j < 8; ++j) {
    const int d = tid + (j << 8);
    float ss = 0.f;
#pragma unroll
    for (int n = 0; n < 16; ++n) {
      float a = A_log[(d << 4) + n];
      float e = __expf(a);
      ss = fmaf(e, e, ss);
      amaxl[n] = fmaxf(amaxl[n], a);
      aminl[n] = fminf(aminl[n], a);
    }
    rn[j] = sqrtf(ss);
  }
  float rm = rn[0];
#pragma unroll
  for (int j = 1; j < 8; ++j) rm = fmaxf(rm, rn[j]);
  red[tid] = rm; __syncthreads();
  for (int s = 128; s > 0; s >>= 1) { if (tid < s) red[tid] = fmaxf(red[tid], red[tid + s]); __syncthreads(); }
  const float rnmax = red[0]; __syncthreads();

#pragma unroll
  for (int n = 0; n < 16; ++n) AM[tid][n] = amaxl[n];
  __syncthreads();
  if (tid < 16) { float m = -1e30f; for (int i = 0; i < 256; ++i) m = fmaxf(m, AM[i][tid]); sAmax[tid] = m; }
  __syncthreads();
#pragma unroll
  for (int n = 0; n < 16; ++n) AM[tid][n] = aminl[n];
  __syncthreads();
  if (tid < 16) { float m = 1e30f; for (int i = 0; i < 256; ++i) m = fminf(m, AM[i][tid]); sAmin[tid] = m; }
  __syncthreads();

  const float irn = 1.f / (rnmax + 1e-8f);
#pragma unroll
  for (int j = 0; j < 8; ++j) {
    const int d = tid + (j << 8);
    const float att = rn[j] * irn;
    const float f = p[j] / psum;
    const float alpha = fminf(fmaxf(f * (1.f - att), 0.f), 1.f);
#pragma unroll
    for (int n = 0; n < 16; ++n) {
      float a = A_log[(d << 4) + n];
      float fl = sAmax[n] + sAmin[n] - a;
      float an = (1.f - alpha) * a + alpha * fl;
      Aws[(d << 4) + n] = -__expf(an);
    }
  }
}

// ---------------------------------------------------------------------------
// Depthwise causal conv (k=4) + bias + SiLU, float4 per thread.
// X (b,l,2048) -> U (b,l,2048)
// ---------------------------------------------------------------------------
__global__ __launch_bounds__(256) void conv_kernel(
    const float* __restrict__ X, const float* __restrict__ cw,
    const float* __restrict__ cb, float* __restrict__ U)
{
  const size_t i4 = ((size_t)blockIdx.x << 8) + threadIdx.x;  // < 4,194,304
  const int e4 = (int)(i4 & 511);
  const size_t row = i4 >> 9;          // b*2048 + l
  const int l = (int)(row & 2047);
  const float* xr = X + (row << 11) + (e4 << 2);
  const float4 z4 = make_float4(0.f, 0.f, 0.f, 0.f);
  float4 x0 = *(const float4*)xr;
  float4 x1 = (l >= 1) ? *(const float4*)(xr - 2048) : z4;
  float4 x2 = (l >= 2) ? *(const float4*)(xr - 4096) : z4;
  float4 x3 = (l >= 3) ? *(const float4*)(xr - 6144) : z4;
  const float4* cwf = (const float4*)cw;
  float4 bi = *(const float4*)(cb + (e4 << 2));
  float x0a[4] = {x0.x, x0.y, x0.z, x0.w};
  float x1a[4] = {x1.x, x1.y, x1.z, x1.w};
  float x2a[4] = {x2.x, x2.y, x2.z, x2.w};
  float x3a[4] = {x3.x, x3.y, x3.z, x3.w};
  float bia[4] = {bi.x, bi.y, bi.z, bi.w};
  float o[4];
#pragma unroll
  for (int c = 0; c < 4; ++c) {
    float4 w = cwf[(e4 << 2) + c];
    float acc = bia[c];
    acc = fmaf(x3a[c], w.x, acc);
    acc = fmaf(x2a[c], w.y, acc);
    acc = fmaf(x1a[c], w.z, acc);
    acc = fmaf(x0a[c], w.w, acc);
    o[c] = silu_(acc);
  }
  *(float4*)(U + (i4 << 2)) = make_float4(o[0], o[1], o[2], o[3]);
}

// ---------------------------------------------------------------------------
// Chunked selective scan (delta in X region stride 2048, z in Z stride 2048).
// ---------------------------------------------------------------------------
__global__ __launch_bounds__(256) void scan_pass1(
    const float* __restrict__ delta, const float* __restrict__ U,
    const float* __restrict__ xdbl, const float* __restrict__ Aws,
    float* __restrict__ cs, float* __restrict__ sdt)
{
  __shared__ float blds[CL * 16];
  const int tid = threadIdx.x;
  const int dg = blockIdx.x & 7;
  const int chunk = (blockIdx.x >> 3) & 31;
  const int b = blockIdx.x >> 8;
  const int d = (dg << 8) | tid;
  const int l0 = chunk * CL;

  for (int i = tid; i < CL * 16; i += 256) {
    int l = i >> 4, j = i & 15;
    blds[i] = xdbl[(size_t)(b * LSEQ + l0 + l) * 96 + 64 + j];
  }
  __syncthreads();

  float Ar[16];
#pragma unroll
  for (int n = 0; n < 16; ++n) Ar[n] = Aws[(d << 4) + n];
  float s[16];
#pragma unroll
  for (int n = 0; n < 16; ++n) s[n] = 0.f;
  float sumdt = 0.f;

  const float* dp = delta + ((size_t)b << 22) + ((size_t)l0 << 11) + d;
  const float* up = U + ((size_t)b << 22) + ((size_t)l0 << 11) + d;

  for (int l = 0; l < CL; ++l) {
    const float dt = dp[(size_t)l << 11];
    const float u = up[(size_t)l << 11];
    sumdt += dt;
    const float du = dt * u;
    const float* bl = &blds[l << 4];
#pragma unroll
    for (int n = 0; n < 16; ++n)
      s[n] = fmaf(s[n], __expf(dt * Ar[n]), du * bl[n]);
  }

  float* csp = cs + ((((size_t)b * NC + chunk) * 2048 + d) << 4);
#pragma unroll
  for (int n = 0; n < 4; ++n)
    *(float4*)(csp + (n << 2)) = make_float4(s[4*n], s[4*n+1], s[4*n+2], s[4*n+3]);
  sdt[((size_t)b * NC + chunk) * 2048 + d] = sumdt;
}

__global__ __launch_bounds__(256) void scan_mid(
    float* __restrict__ cs, const float* __restrict__ sdt,
    const float* __restrict__ Aws)
{
  const int b = blockIdx.x >> 3;
  const int d = ((blockIdx.x & 7) << 8) | threadIdx.x;
  float Ar[16];
#pragma unroll
  for (int n = 0; n < 16; ++n) Ar[n] = Aws[(d << 4) + n];
  float si[16];
#pragma unroll
  for (int n = 0; n < 16; ++n) si[n] = 0.f;

  for (int c = 0; c < NC; ++c) {
    const size_t base = ((size_t)b * NC + c) * 2048 + d;
    float* csp = cs + (base << 4);
    float sl[16];
#pragma unroll
    for (int n = 0; n < 4; ++n) {
      float4 v = *(const float4*)(csp + (n << 2));
      sl[4*n] = v.x; sl[4*n+1] = v.y; sl[4*n+2] = v.z; sl[4*n+3] = v.w;
    }
    const float sm = sdt[base];
#pragma unroll
    for (int n = 0; n < 4; ++n)
      *(float4*)(csp + (n << 2)) = make_float4(si[4*n], si[4*n+1], si[4*n+2], si[4*n+3]);
#pragma unroll
    for (int n = 0; n < 16; ++n)
      si[n] = fmaf(si[n], __expf(sm * Ar[n]), sl[n]);
  }
}

__global__ __launch_bounds__(256) void scan_pass3(
    const float* __restrict__ delta, const float* __restrict__ Z,
    float* __restrict__ U,
    const float* __restrict__ xdbl, const float* __restrict__ Aws,
    const float* __restrict__ Dp, const float* __restrict__ cs)
{
  __shared__ float bclds[CL * 32];
  const int tid = threadIdx.x;
  const int dg = blockIdx.x & 7;
  const int chunk = (blockIdx.x >> 3) & 31;
  const int b = blockIdx.x >> 8;
  const int d = (dg << 8) | tid;
  const int l0 = chunk * CL;

  for (int i = tid; i < CL * 32; i += 256) {
    int l = i >> 5, j = i & 31;
    bclds[i] = xdbl[(size_t)(b * LSEQ + l0 + l) * 96 + 64 + j];
  }
  __syncthreads();

  float Ar[16];
#pragma unroll
  for (int n = 0; n < 16; ++n) Ar[n] = Aws[(d << 4) + n];
  const float Dd = Dp[d];

  const float* csp = cs + ((((size_t)b * NC + chunk) * 2048 + d) << 4);
  float s[16];
#pragma unroll
  for (int n = 0; n < 4; ++n) {
    float4 v = *(const float4*)(csp + (n << 2));
    s[4*n] = v.x; s[4*n+1] = v.y; s[4*n+2] = v.z; s[4*n+3] = v.w;
  }

  const float* dp = delta + ((size_t)b << 22) + ((size_t)l0 << 11) + d;
  const float* zp = Z + ((size_t)b << 22) + ((size_t)l0 << 11) + d;
  float* up = U + ((size_t)b << 22) + ((size_t)l0 << 11) + d;

  for (int l = 0; l < CL; ++l) {
    const float dt = dp[(size_t)l << 11];
    const float u = up[(size_t)l << 11];
    const float z = zp[(size_t)l << 11];
    const float du = dt * u;
    const float* bcl = &bclds[l << 5];
    float y = 0.f;
#pragma unroll
    for (int n = 0; n < 16; ++n) {
      s[n] = fmaf(s[n], __expf(dt * Ar[n]), du * bcl[n]);
      y = fmaf(s[n], bcl[16 + n], y);
    }
    const float yv = fmaf(u, Dd, y);
    up[(size_t)l << 11] = yv * silu_(z);
  }
}

// ---------------------------------------------------------------------------
extern "C" void kernel_launch(void* const* d_in, const int* in_sizes, int n_in,
                              void* d_out, int out_size, void* d_ws, size_t ws_size,
                              hipStream_t stream)
{
  const float* hs         = (const float*)d_in[0];
  const float* in_proj_w  = (const float*)d_in[4];
  const float* conv_w     = (const float*)d_in[5];
  const float* conv_b     = (const float*)d_in[6];
  const float* x_proj_w   = (const float*)d_in[7];
  const float* dt_proj_w  = (const float*)d_in[8];
  const float* dt_proj_b  = (const float*)d_in[9];
  const float* A_log      = (const float*)d_in[10];
  const float* Dp         = (const float*)d_in[11];
  const float* out_proj_w = (const float*)d_in[12];
  float* out = (float*)d_out;
  float* ws = (float*)d_ws;

  float* X     = ws + OFF_X;
  float* Z     = ws + OFF_Z;
  float* U     = ws + OFF_U;
  float* cs    = ws + OFF_CS;
  float* sdt   = ws + OFF_SDT;
  float* xdbl  = ws + OFF_XDBL;
  float* feats = ws + OFF_FEAT;
  float* Aws   = ws + OFF_AWS;
  unsigned short* A1s = (unsigned short*)(ws + OFF_S);
  unsigned short* B1s = (unsigned short*)(ws + OFF_B1);
  unsigned short* B2s = (unsigned short*)(ws + OFF_B1);

  const dim3 blk(256);

  // 0. split hs (2,097,152 float4s) + in_proj_w (1,048,576 float4s)
  split2_w<<<12288, blk, 0, stream>>>(hs, A1s, 10, (size_t)2097152,
                                      in_proj_w, B1s, 10);
  // 1a. X half: hs @ in_proj_w[0:2048]^T, full 3-pass (M=8192,N=2048,K=1024)
  gemm_mfma<3, 0><<<dim3(16, 64), blk, 0, stream>>>(A1s, B1s, X, 1024, 2048, 1);
  // 1b. Z half: hs @ in_proj_w[2048:4096]^T, hi*hi only (silu-gate budget)
  gemm_mfma<1, 0><<<dim3(16, 64), blk, 0, stream>>>(A1s, B1s + (size_t)2048 * 2048, Z, 1024, 2048, 1);
  // 2. channel-alignment features (reads X)
  feat_kernel<<<4096, blk, 0, stream>>>(X, feats);
  // 3. depthwise conv + silu (X -> U)
  conv_kernel<<<16384, blk, 0, stream>>>(X, conv_w, conv_b, U);
  // 3b. split out_proj_w (524,288 float4s) -> 2048 blocks (overlays dead B1s)
  split2_w<<<2048, blk, 0, stream>>>(out_proj_w, B2s, 11, (size_t)524288,
                                     out_proj_w, B2s, 11);
  // 4. loss + norms + alpha + A
  alpha_kernel<<<1, blk, 0, stream>>>(feats, A_log, Aws, out + 8388608);
  // 5. x_dbl = U @ x_proj_w^T (M=8192,N=96,K=2048) — split-K=4 into cs region
  gemm_nt<0><<<dim3(2, 128, 4), blk, 0, stream>>>(U, DI, x_proj_w, DI, cs, 96, 96, 512, nullptr, (size_t)786432);
  reduce4<<<768, blk, 0, stream>>>(cs, xdbl, (size_t)786432);
  // 6. delta = softplus(x_dbl[:, :64] @ dt_proj_w^T + b) -> X region (dead x)
  gemm_nt<1><<<dim3(32, 128, 1), blk, 0, stream>>>(xdbl, 96, dt_proj_w, 64, X, DI, DI, 64, dt_proj_b, 0);
  // 7. chunked selective scan; y overwrites U (fp32, stays fp32)
  scan_pass1<<<1024, blk, 0, stream>>>(X, U, xdbl, Aws, cs, sdt);
  scan_mid<<<32, blk, 0, stream>>>(cs, sdt, Aws);
  scan_pass3<<<1024, blk, 0, stream>>>(X, Z, U, xdbl, Aws, Dp, cs);
  // 8. out = y @ out_proj_w^T  (MFMA, A=fp32 y split in-register during staging)
  gemm_mfma<3, 1><<<dim3(8, 64), blk, 0, stream>>>(U, B2s, out, 2048, 1024, 0);
}